// Round 1
// baseline (845.938 us; speedup 1.0000x reference)
//
#include <hip/hip_runtime.h>
#include <cstdint>
#include <cmath>

// ---------------------------------------------------------------------------
// RegionSelection on MI355X (gfx950)
//
// Pipeline:
//   K1: h1 = relu(W1 @ feat + b1)    GEMM 512x1024 @ 1024x32768  (fp32 VALU)
//   K2: h2 = relu(W2 @ h1 + b2)      GEMM 256x512  @ 512x32768
//   K3: att = (sigmoid(w3 . h2 + b3) + cam) * 0.5   (cam resize is identity)
//   K4: 3x iterative argmax + 11x11 suppression per batch -> y1,x1 + coords
//   K5: crop 96 regions of 3x384x384 from original
//
// Scratch: h1/h2 live in the (not-yet-written) regions area of d_out.
// d_ws holds only the 96 (y1,x1) int pairs.
// ---------------------------------------------------------------------------

typedef float f4 __attribute__((ext_vector_type(4)));

#define M_PIX 32768
#define REGIONS_ELEMS 42467328   // 96*3*384*384
#define COORDS_OFF 42467328
#define ATT_OFF 42467712
#define H1_OFF 0
#define H2_OFF 16777216          // 512*32768

// ---------------------------------------------------------------------------
// Tiled fp32 GEMM: OUT[n][p] = relu(bias[n] + sum_k W[n][k] * F[k][p])
// Tile: 64 neurons x 128 pixels, BK=16. 256 threads, each 4n x 8p accumulators.
// use_feat=1: F is features [B=32][C=K][1024] -> per-tile base, row stride 1024.
// use_feat=0: F row stride = fstride (32768), base = F + px0.
// ---------------------------------------------------------------------------
__global__ __launch_bounds__(256) void mlp_gemm(
    const float* __restrict__ W, const float* __restrict__ F,
    const float* __restrict__ bias, float* __restrict__ OUT,
    int Kdim, long fstride, int use_feat)
{
    __shared__ float Wt[16][64];     // [k][n]  (transposed stage)
    __shared__ float Ft[16][128];    // [k][p]

    const int t = threadIdx.x;
    const int px0 = blockIdx.x * 128;
    const int n0  = blockIdx.y * 64;

    const float* F0;
    if (use_feat) F0 = F + ((size_t)(px0 >> 10) * 1048576) + (px0 & 1023);
    else          F0 = F + px0;

    const int tp = t & 15;       // pixel group: pixels {4tp..4tp+3} and {64+4tp..}
    const int tn = t >> 4;       // neuron group: neurons {4tn..4tn+3}

    float acc[4][8];
    #pragma unroll
    for (int i = 0; i < 4; ++i)
        #pragma unroll
        for (int j = 0; j < 8; ++j) acc[i][j] = 0.0f;

    // staging indices
    const int fr = t >> 5;            // 0..7  (F tile row)
    const int fc = (t & 31) * 4;      // 0..124 (F tile col, float4)
    const int wn = t >> 2;            // 0..63 (W tile neuron)
    const int wk = (t & 3) * 4;       // 0,4,8,12 (W tile k, float4)

    for (int k0 = 0; k0 < Kdim; k0 += 16) {
        // stage F tile: 16 rows x 128 px
        *(f4*)&Ft[fr][fc]     = *(const f4*)(F0 + (size_t)(k0 + fr) * fstride + fc);
        *(f4*)&Ft[fr + 8][fc] = *(const f4*)(F0 + (size_t)(k0 + fr + 8) * fstride + fc);
        // stage W tile transposed: Wt[k][n]
        {
            f4 wv = *(const f4*)(W + (size_t)(n0 + wn) * Kdim + k0 + wk);
            Wt[wk + 0][wn] = wv.x;
            Wt[wk + 1][wn] = wv.y;
            Wt[wk + 2][wn] = wv.z;
            Wt[wk + 3][wn] = wv.w;
        }
        __syncthreads();

        #pragma unroll
        for (int k = 0; k < 16; ++k) {
            f4 wf = *(const f4*)&Wt[k][tn * 4];
            f4 fa = *(const f4*)&Ft[k][tp * 4];
            f4 fb = *(const f4*)&Ft[k][64 + tp * 4];
            #pragma unroll
            for (int i = 0; i < 4; ++i) {
                acc[i][0] = fmaf(wf[i], fa[0], acc[i][0]);
                acc[i][1] = fmaf(wf[i], fa[1], acc[i][1]);
                acc[i][2] = fmaf(wf[i], fa[2], acc[i][2]);
                acc[i][3] = fmaf(wf[i], fa[3], acc[i][3]);
                acc[i][4] = fmaf(wf[i], fb[0], acc[i][4]);
                acc[i][5] = fmaf(wf[i], fb[1], acc[i][5]);
                acc[i][6] = fmaf(wf[i], fb[2], acc[i][6]);
                acc[i][7] = fmaf(wf[i], fb[3], acc[i][7]);
            }
        }
        __syncthreads();
    }

    // epilogue: +bias, relu, store
    #pragma unroll
    for (int i = 0; i < 4; ++i) {
        const int n = n0 + tn * 4 + i;
        const float bv = bias[n];
        float* dst = OUT + (size_t)n * M_PIX + px0;
        f4 v0, v1;
        #pragma unroll
        for (int j = 0; j < 4; ++j) {
            v0[j] = fmaxf(acc[i][j] + bv, 0.0f);
            v1[j] = fmaxf(acc[i][4 + j] + bv, 0.0f);
        }
        *(f4*)(dst + tp * 4)      = v0;
        *(f4*)(dst + 64 + tp * 4) = v1;
    }
}

// ---------------------------------------------------------------------------
// K3: att[p] = (sigmoid(b3 + sum_k w3[k]*h2[k][p]) + cam[p]) * 0.5
// ---------------------------------------------------------------------------
__global__ __launch_bounds__(256) void layer3_att(
    const float* __restrict__ h2, const float* __restrict__ w3,
    const float* __restrict__ b3, const float* __restrict__ cam,
    float* __restrict__ att)
{
    const int p = blockIdx.x * 256 + threadIdx.x;
    float s = b3[0];
    #pragma unroll 8
    for (int k = 0; k < 256; ++k)
        s = fmaf(w3[k], h2[(size_t)k * M_PIX + p], s);
    const float sg = 1.0f / (1.0f + expf(-s));
    att[p] = (sg + cam[p]) * 0.5f;
}

// ---------------------------------------------------------------------------
// K4: per-batch 3x (argmax + suppression). 1 wave per batch.
// coords written as float32 (harness reads d_out as one float buffer).
// (y1,x1) ints -> d_ws for the crop kernel.
// ---------------------------------------------------------------------------
__global__ __launch_bounds__(64) void peaks_kernel(
    const float* __restrict__ att, float* __restrict__ coords,
    int* __restrict__ wsyx)
{
    const int b = blockIdx.x;
    const int lane = threadIdx.x;
    __shared__ float s[1024];
    for (int i = lane; i < 1024; i += 64) s[i] = att[b * 1024 + i];
    __syncthreads();

    for (int kpk = 0; kpk < 3; ++kpk) {
        float bv = -1.0f;
        int bi = 0x7fffffff;
        for (int i = lane; i < 1024; i += 64) {
            float v = s[i];
            if (v > bv) { bv = v; bi = i; }   // ascending i => first-max per lane
        }
        // wave argmax, tie -> smaller flat index (matches jnp.argmax)
        for (int off = 32; off >= 1; off >>= 1) {
            float ov = __shfl_down(bv, off);
            int   oi = __shfl_down(bi, off);
            if (ov > bv || (ov == bv && oi < bi)) { bv = ov; bi = oi; }
        }
        bv = __shfl(bv, 0);
        bi = __shfl(bi, 0);

        int fy, fx;
        if (bv > 0.0f) { fy = bi >> 5; fx = bi & 31; }
        else           { fy = 16;      fx = 16; }

        // suppress 11x11 window
        for (int i = lane; i < 1024; i += 64) {
            const int y = i >> 5, x = i & 31;
            const int dy = y > fy ? y - fy : fy - y;
            const int dx = x > fx ? x - fx : fx - x;
            if (dy <= 5 && dx <= 5) s[i] = 0.0f;
        }
        __syncthreads();

        if (lane == 0) {
            int y1 = fy * 16 - 192; y1 = y1 < 0 ? 0 : (y1 > 128 ? 128 : y1);
            int x1 = fx * 16 - 192; x1 = x1 < 0 ? 0 : (x1 > 128 ? 128 : x1);
            const int idx = b * 3 + kpk;
            coords[idx * 4 + 0] = (float)x1;
            coords[idx * 4 + 1] = (float)y1;
            coords[idx * 4 + 2] = (float)(x1 + 384);
            coords[idx * 4 + 3] = (float)(y1 + 384);
            wsyx[idx * 2 + 0] = y1;
            wsyx[idx * 2 + 1] = x1;
        }
        __syncthreads();
    }
}

// ---------------------------------------------------------------------------
// K5: crop 96 regions x 3ch x 384x384 from original (x1 is 16-float aligned).
// One float4 per thread. Output layout [r][c][row][col] == flat id*4.
// ---------------------------------------------------------------------------
__global__ __launch_bounds__(256) void crop_kernel(
    const float* __restrict__ orig, const int* __restrict__ wsyx,
    float* __restrict__ out)
{
    const int id = blockIdx.x * 256 + threadIdx.x;       // < 96*3*384*96
    const int r    = id / (3 * 384 * 96);
    const int rem  = id - r * (3 * 384 * 96);
    const int c    = rem / (384 * 96);
    const int rem2 = rem - c * (384 * 96);
    const int row  = rem2 / 96;
    const int col  = (rem2 - row * 96) * 4;
    const int b = r / 3;
    const int y1 = wsyx[r * 2], x1 = wsyx[r * 2 + 1];
    const float* src = orig + (size_t)b * 786432 + (size_t)c * 262144
                     + (size_t)(y1 + row) * 512 + x1 + col;
    *(f4*)(out + (size_t)id * 4) = *(const f4*)src;
}

// ---------------------------------------------------------------------------
extern "C" void kernel_launch(void* const* d_in, const int* in_sizes, int n_in,
                              void* d_out, int out_size, void* d_ws, size_t ws_size,
                              hipStream_t stream)
{
    const float* features = (const float*)d_in[0];  // [32,1024,32,32]
    const float* cam      = (const float*)d_in[1];  // [32,32,32]
    const float* original = (const float*)d_in[2];  // [32,3,512,512]
    const float* w1 = (const float*)d_in[3];        // [512,1024]
    const float* b1 = (const float*)d_in[4];
    const float* w2 = (const float*)d_in[5];        // [256,512]
    const float* b2 = (const float*)d_in[6];
    const float* w3 = (const float*)d_in[7];        // [1,256]
    const float* b3 = (const float*)d_in[8];

    float* out    = (float*)d_out;
    float* h1     = out + H1_OFF;        // scratch in regions area
    float* h2     = out + H2_OFF;        // scratch in regions area
    float* att    = out + ATT_OFF;       // final output slot
    float* coords = out + COORDS_OFF;    // final output slot
    int*   wsyx   = (int*)d_ws;

    dim3 b256(256);
    // K1: 512 x 32768 <- [512x1024] @ [1024 x 32768]
    mlp_gemm<<<dim3(256, 8), b256, 0, stream>>>(w1, features, b1, h1, 1024, 1024L, 1);
    // K2: 256 x 32768 <- [256x512] @ [512 x 32768]
    mlp_gemm<<<dim3(256, 4), b256, 0, stream>>>(w2, h1, b2, h2, 512, 32768L, 0);
    // K3
    layer3_att<<<dim3(128), b256, 0, stream>>>(h2, w3, b3, cam, att);
    // K4
    peaks_kernel<<<dim3(32), dim3(64), 0, stream>>>(att, coords, wsyx);
    // K5: 42,467,328 floats / 4 / 256 = 41472 blocks
    crop_kernel<<<dim3(41472), b256, 0, stream>>>(original, wsyx, out);
}

// Round 2
// 791.391 us; speedup vs baseline: 1.0689x; 1.0689x over previous
//
#include <hip/hip_runtime.h>
#include <cstdint>
#include <cmath>

// ---------------------------------------------------------------------------
// RegionSelection on MI355X (gfx950)
//
// Pipeline:
//   K1: h1 = relu(W1 @ feat + b1)    GEMM 512x1024 @ 1024x32768  (fp32 VALU)
//   K2: h2 = relu(W2 @ h1 + b2)      GEMM 256x512  @ 512x32768
//   K3: att = (sigmoid(w3 . h2 + b3) + cam) * 0.5   (cam resize is identity)
//   K4: 3x iterative argmax + 11x11 suppression per batch -> y1,x1 + coords
//   K5: crop 96 regions of 3x384x384 from original
//
// R1 change: GEMM register tile 4nx8p -> 8nx8p (block tile 128n x 128px).
// LDS instrs per FMA drop 3x; was LDS-pipe bound (VALUBusy 64%).
//
// Scratch: h1/h2 live in the (not-yet-written) regions area of d_out.
// d_ws holds only the 96 (y1,x1) int pairs.
// ---------------------------------------------------------------------------

typedef float f4 __attribute__((ext_vector_type(4)));

#define M_PIX 32768
#define COORDS_OFF 42467328      // 96*3*384*384
#define ATT_OFF 42467712
#define H1_OFF 0
#define H2_OFF 16777216          // 512*32768

// ---------------------------------------------------------------------------
// Tiled fp32 GEMM: OUT[n][p] = relu(bias[n] + sum_k W[n][k] * F[k][p])
// Block tile: 128 neurons x 128 pixels, BK=16. 256 threads, 8n x 8p each.
// use_feat=1: F is features [B=32][C=K][1024] -> per-image base, row stride 1024.
// use_feat=0: F row stride = fstride (32768), base = F + px0.
// ---------------------------------------------------------------------------
__global__ __launch_bounds__(256) void mlp_gemm(
    const float* __restrict__ W, const float* __restrict__ F,
    const float* __restrict__ bias, float* __restrict__ OUT,
    int Kdim, long fstride, int use_feat)
{
    __shared__ float Wt[16][128];    // [k][n]  (transposed stage)
    __shared__ float Ft[16][128];    // [k][p]

    const int t = threadIdx.x;
    const int px0 = blockIdx.x * 128;
    const int n0  = blockIdx.y * 128;

    const float* F0;
    if (use_feat) F0 = F + ((size_t)(px0 >> 10) * 1048576) + (px0 & 1023);
    else          F0 = F + px0;

    const int tp = t & 15;       // pixel group: px {4tp..} and {64+4tp..}
    const int tn = t >> 4;       // 0..15: neurons {4tn..} and {64+4tn..}

    float acc[8][8];
    #pragma unroll
    for (int i = 0; i < 8; ++i)
        #pragma unroll
        for (int j = 0; j < 8; ++j) acc[i][j] = 0.0f;

    // staging indices
    const int fr = t >> 5;            // 0..7   (F tile row; also +8)
    const int fc = (t & 31) * 4;      // 0..124 (F tile col, float4)
    const int wn = t >> 1;            // 0..127 (W tile neuron)
    const int wk = (t & 1) * 8;       // 0 or 8 (W tile k base, 2x float4)

    for (int k0 = 0; k0 < Kdim; k0 += 16) {
        // stage F tile: 16 rows x 128 px
        *(f4*)&Ft[fr][fc]     = *(const f4*)(F0 + (size_t)(k0 + fr) * fstride + fc);
        *(f4*)&Ft[fr + 8][fc] = *(const f4*)(F0 + (size_t)(k0 + fr + 8) * fstride + fc);
        // stage W tile transposed: Wt[k][n]  (8 k per thread for one n)
        {
            const float* wp = W + (size_t)(n0 + wn) * Kdim + k0 + wk;
            f4 wa = *(const f4*)(wp);
            f4 wb = *(const f4*)(wp + 4);
            Wt[wk + 0][wn] = wa.x;
            Wt[wk + 1][wn] = wa.y;
            Wt[wk + 2][wn] = wa.z;
            Wt[wk + 3][wn] = wa.w;
            Wt[wk + 4][wn] = wb.x;
            Wt[wk + 5][wn] = wb.y;
            Wt[wk + 6][wn] = wb.z;
            Wt[wk + 7][wn] = wb.w;
        }
        __syncthreads();

        #pragma unroll
        for (int k = 0; k < 16; ++k) {
            f4 w0 = *(const f4*)&Wt[k][tn * 4];
            f4 w1 = *(const f4*)&Wt[k][64 + tn * 4];
            f4 fa = *(const f4*)&Ft[k][tp * 4];
            f4 fb = *(const f4*)&Ft[k][64 + tp * 4];
            #pragma unroll
            for (int i = 0; i < 4; ++i) {
                #pragma unroll
                for (int j = 0; j < 4; ++j) {
                    acc[i][j]         = fmaf(w0[i], fa[j], acc[i][j]);
                    acc[i][4 + j]     = fmaf(w0[i], fb[j], acc[i][4 + j]);
                    acc[4 + i][j]     = fmaf(w1[i], fa[j], acc[4 + i][j]);
                    acc[4 + i][4 + j] = fmaf(w1[i], fb[j], acc[4 + i][4 + j]);
                }
            }
        }
        __syncthreads();
    }

    // epilogue: +bias, relu, store (8 n-rows x 2 f4 groups)
    #pragma unroll
    for (int i = 0; i < 8; ++i) {
        const int n = n0 + (i < 4 ? tn * 4 + i : 64 + tn * 4 + (i - 4));
        const float bv = bias[n];
        float* dst = OUT + (size_t)n * M_PIX + px0;
        f4 v0, v1;
        #pragma unroll
        for (int j = 0; j < 4; ++j) {
            v0[j] = fmaxf(acc[i][j] + bv, 0.0f);
            v1[j] = fmaxf(acc[i][4 + j] + bv, 0.0f);
        }
        *(f4*)(dst + tp * 4)      = v0;
        *(f4*)(dst + 64 + tp * 4) = v1;
    }
}

// ---------------------------------------------------------------------------
// K3: att[p] = (sigmoid(b3 + sum_k w3[k]*h2[k][p]) + cam[p]) * 0.5
// ---------------------------------------------------------------------------
__global__ __launch_bounds__(256) void layer3_att(
    const float* __restrict__ h2, const float* __restrict__ w3,
    const float* __restrict__ b3, const float* __restrict__ cam,
    float* __restrict__ att)
{
    const int p = blockIdx.x * 256 + threadIdx.x;
    float s = b3[0];
    #pragma unroll 8
    for (int k = 0; k < 256; ++k)
        s = fmaf(w3[k], h2[(size_t)k * M_PIX + p], s);
    const float sg = 1.0f / (1.0f + expf(-s));
    att[p] = (sg + cam[p]) * 0.5f;
}

// ---------------------------------------------------------------------------
// K4: per-batch 3x (argmax + suppression). 1 wave per batch.
// coords written as float32 (harness reads d_out as one float buffer).
// (y1,x1) ints -> d_ws for the crop kernel.
// ---------------------------------------------------------------------------
__global__ __launch_bounds__(64) void peaks_kernel(
    const float* __restrict__ att, float* __restrict__ coords,
    int* __restrict__ wsyx)
{
    const int b = blockIdx.x;
    const int lane = threadIdx.x;
    __shared__ float s[1024];
    for (int i = lane; i < 1024; i += 64) s[i] = att[b * 1024 + i];
    __syncthreads();

    for (int kpk = 0; kpk < 3; ++kpk) {
        float bv = -1.0f;
        int bi = 0x7fffffff;
        for (int i = lane; i < 1024; i += 64) {
            float v = s[i];
            if (v > bv) { bv = v; bi = i; }   // ascending i => first-max per lane
        }
        // wave argmax, tie -> smaller flat index (matches jnp.argmax)
        for (int off = 32; off >= 1; off >>= 1) {
            float ov = __shfl_down(bv, off);
            int   oi = __shfl_down(bi, off);
            if (ov > bv || (ov == bv && oi < bi)) { bv = ov; bi = oi; }
        }
        bv = __shfl(bv, 0);
        bi = __shfl(bi, 0);

        int fy, fx;
        if (bv > 0.0f) { fy = bi >> 5; fx = bi & 31; }
        else           { fy = 16;      fx = 16; }

        // suppress 11x11 window
        for (int i = lane; i < 1024; i += 64) {
            const int y = i >> 5, x = i & 31;
            const int dy = y > fy ? y - fy : fy - y;
            const int dx = x > fx ? x - fx : fx - x;
            if (dy <= 5 && dx <= 5) s[i] = 0.0f;
        }
        __syncthreads();

        if (lane == 0) {
            int y1 = fy * 16 - 192; y1 = y1 < 0 ? 0 : (y1 > 128 ? 128 : y1);
            int x1 = fx * 16 - 192; x1 = x1 < 0 ? 0 : (x1 > 128 ? 128 : x1);
            const int idx = b * 3 + kpk;
            coords[idx * 4 + 0] = (float)x1;
            coords[idx * 4 + 1] = (float)y1;
            coords[idx * 4 + 2] = (float)(x1 + 384);
            coords[idx * 4 + 3] = (float)(y1 + 384);
            wsyx[idx * 2 + 0] = y1;
            wsyx[idx * 2 + 1] = x1;
        }
        __syncthreads();
    }
}

// ---------------------------------------------------------------------------
// K5: crop 96 regions x 3ch x 384x384 from original (x1 is 16-float aligned).
// One float4 per thread. Output layout [r][c][row][col] == flat id*4.
// ---------------------------------------------------------------------------
__global__ __launch_bounds__(256) void crop_kernel(
    const float* __restrict__ orig, const int* __restrict__ wsyx,
    float* __restrict__ out)
{
    const int id = blockIdx.x * 256 + threadIdx.x;       // < 96*3*384*96
    const int r    = id / (3 * 384 * 96);
    const int rem  = id - r * (3 * 384 * 96);
    const int c    = rem / (384 * 96);
    const int rem2 = rem - c * (384 * 96);
    const int row  = rem2 / 96;
    const int col  = (rem2 - row * 96) * 4;
    const int b = r / 3;
    const int y1 = wsyx[r * 2], x1 = wsyx[r * 2 + 1];
    const float* src = orig + (size_t)b * 786432 + (size_t)c * 262144
                     + (size_t)(y1 + row) * 512 + x1 + col;
    *(f4*)(out + (size_t)id * 4) = *(const f4*)src;
}

// ---------------------------------------------------------------------------
extern "C" void kernel_launch(void* const* d_in, const int* in_sizes, int n_in,
                              void* d_out, int out_size, void* d_ws, size_t ws_size,
                              hipStream_t stream)
{
    const float* features = (const float*)d_in[0];  // [32,1024,32,32]
    const float* cam      = (const float*)d_in[1];  // [32,32,32]
    const float* original = (const float*)d_in[2];  // [32,3,512,512]
    const float* w1 = (const float*)d_in[3];        // [512,1024]
    const float* b1 = (const float*)d_in[4];
    const float* w2 = (const float*)d_in[5];        // [256,512]
    const float* b2 = (const float*)d_in[6];
    const float* w3 = (const float*)d_in[7];        // [1,256]
    const float* b3 = (const float*)d_in[8];

    float* out    = (float*)d_out;
    float* h1     = out + H1_OFF;        // scratch in regions area
    float* h2     = out + H2_OFF;        // scratch in regions area
    float* att    = out + ATT_OFF;       // final output slot
    float* coords = out + COORDS_OFF;    // final output slot
    int*   wsyx   = (int*)d_ws;

    dim3 b256(256);
    // K1: 512 x 32768 <- [512x1024] @ [1024 x 32768]
    mlp_gemm<<<dim3(256, 4), b256, 0, stream>>>(w1, features, b1, h1, 1024, 1024L, 1);
    // K2: 256 x 32768 <- [256x512] @ [512 x 32768]
    mlp_gemm<<<dim3(256, 2), b256, 0, stream>>>(w2, h1, b2, h2, 512, 32768L, 0);
    // K3
    layer3_att<<<dim3(128), b256, 0, stream>>>(h2, w3, b3, cam, att);
    // K4
    peaks_kernel<<<dim3(32), dim3(64), 0, stream>>>(att, coords, wsyx);
    // K5: 42,467,328 floats / 4 / 256 = 41472 blocks
    crop_kernel<<<dim3(41472), b256, 0, stream>>>(original, wsyx, out);
}